// Round 1
// baseline (659.889 us; speedup 1.0000x reference)
//
#include <hip/hip_runtime.h>
#include <hip/hip_bf16.h>

#define B_  2048
#define L_  200
#define D_  128
#define H0_ 80
#define H1_ 40

// One block per batch element b. 256 threads.
// Layer0 factorization: feat@W0 = hist@(W0a+W0c+diag(tgt)W0d) + [tgt@(W0b-W0c)+b0]
__global__ __launch_bounds__(256, 2) void din_kernel(
    const float* __restrict__ hist,   // (B,L,D)
    const float* __restrict__ tgt,    // (B,D)
    const int*   __restrict__ mask,   // (B,L)
    const float* __restrict__ W0,     // (512,80)
    const float* __restrict__ b0,     // (80)
    const float* __restrict__ W1,     // (80,40)
    const float* __restrict__ b1,     // (40)
    const float* __restrict__ W2,     // (40,1)
    const float* __restrict__ b2,     // (1)
    float* __restrict__ out)          // [B*128 user_interest | B*200 attn]
{
    // LDS budget: 40960+12800+10368+512+320+160+160+32 = 65312 B (<= 64 KiB)
    __shared__ float4 w0q[32 * H0_];   // W0eff interleaved: w0q[d4*80+h] = {w[4d4..4d4+3][h]}
    __shared__ float  w1s[H0_ * H1_];  // W1 as-is [d][h]
    __shared__ float  h0s[32 * 81];    // h0 tile (stride 81 = conflict-free), reused for attn
    __shared__ float  tg[D_];
    __shared__ float  beff[H0_];
    __shared__ float  b1s[H1_];
    __shared__ float  w2s[H1_];
    __shared__ float  red[8];

    const int tid = threadIdx.x;
    const int b   = blockIdx.x;
    float* attn_out = out + (size_t)B_ * D_ + (size_t)b * L_; // also score scratch
    float* ui_out   = out + (size_t)b * D_;

    if (tid < D_)  tg[tid]  = tgt[(size_t)b * D_ + tid];
    if (tid < H1_) { b1s[tid] = b1[tid]; w2s[tid] = W2[tid]; }
    for (int i = tid; i < H0_ * H1_; i += 256) w1s[i] = W1[i];
    __syncthreads();

    // Build W0eff (coalesced global reads; LDS scatter write once per block)
    float* w0f = (float*)w0q;
    for (int i = tid; i < D_ * H0_; i += 256) {      // i = d*80 + h
        int d = i / H0_, h = i - d * H0_;
        float v = W0[i] + W0[256 * H0_ + i] + tg[d] * W0[384 * H0_ + i];
        w0f[((d >> 2) * H0_ + h) * 4 + (d & 3)] = v;
    }
    // beff[h] = b0[h] + sum_d tg[d]*(W0b - W0c)[d][h]
    if (tid < H0_) {
        float s = b0[tid];
        for (int d = 0; d < D_; ++d)
            s += tg[d] * (W0[(128 + d) * H0_ + tid] - W0[(256 + d) * H0_ + tid]);
        beff[tid] = s;
    }
    __syncthreads();

    const int hg = tid & 7;    // 8 h-groups
    const int lt = tid >> 3;   // 32 l-slots

    for (int l0 = 0; l0 < L_; l0 += 32) {
        int l  = l0 + lt;
        int lc = (l < L_) ? l : (L_ - 1);
        const float4* arow = (const float4*)(hist + ((size_t)b * L_ + lc) * D_);

        // ---- layer 0: 10 outputs per thread, dot-128 ----
        float acc[10];
        #pragma unroll
        for (int j = 0; j < 10; ++j) acc[j] = 0.f;
        #pragma unroll 4
        for (int d4 = 0; d4 < 32; ++d4) {
            float4 a = arow[d4];
            #pragma unroll
            for (int hh = 0; hh < 10; ++hh) {
                float4 w = w0q[d4 * H0_ + (hg * 10 + hh)];
                acc[hh] += a.x * w.x + a.y * w.y + a.z * w.z + a.w * w.w;
            }
        }
        #pragma unroll
        for (int hh = 0; hh < 10; ++hh) {
            int h = hg * 10 + hh;
            float v = acc[hh] + beff[h];
            h0s[lt * 81 + h] = v > 0.f ? v : 0.f;
        }
        __syncthreads();

        // ---- layer 1 (5 h1 per thread, regs) + layer 2 fused ----
        float acc1[5];
        #pragma unroll
        for (int j = 0; j < 5; ++j) acc1[j] = 0.f;
        #pragma unroll 4
        for (int d = 0; d < H0_; ++d) {
            float a = h0s[lt * 81 + d];
            #pragma unroll
            for (int hh = 0; hh < 5; ++hh)
                acc1[hh] += a * w1s[d * H1_ + hg * 5 + hh];
        }
        float p = 0.f;
        #pragma unroll
        for (int hh = 0; hh < 5; ++hh) {
            int h = hg * 5 + hh;
            float v = acc1[hh] + b1s[h];
            v = v > 0.f ? v : 0.f;
            p += v * w2s[h];
        }
        // reduce over the 8 h-group lanes (consecutive lanes, width-8 segments)
        p += __shfl_down(p, 4, 8);
        p += __shfl_down(p, 2, 8);
        p += __shfl_down(p, 1, 8);
        if (hg == 0 && l < L_) attn_out[l] = p + b2[0];
        __syncthreads();
    }

    // ---- softmax over L with mask ----
    float sc;
    if (tid < L_) {
        sc = attn_out[tid];
        if (mask[(size_t)b * L_ + tid] == 0) sc -= 1e9f;
    } else {
        sc = -3.0e38f;
    }
    float m = sc;
    #pragma unroll
    for (int off = 32; off >= 1; off >>= 1)
        m = fmaxf(m, __shfl_xor(m, off, 64));
    int wid = tid >> 6;
    if ((tid & 63) == 0) red[wid] = m;
    __syncthreads();
    m = fmaxf(fmaxf(red[0], red[1]), fmaxf(red[2], red[3]));
    float e = (tid < L_) ? __expf(sc - m) : 0.f;
    float s = e;
    #pragma unroll
    for (int off = 32; off >= 1; off >>= 1)
        s += __shfl_xor(s, off, 64);
    if ((tid & 63) == 0) red[4 + wid] = s;
    __syncthreads();
    s = red[4] + red[5] + red[6] + red[7];
    float inv = 1.0f / s;
    if (tid < L_) {
        float av = e * inv;
        attn_out[tid] = av;
        h0s[tid] = av;           // reuse LDS for weighted sum
    }
    __syncthreads();

    // ---- user_interest[d] = sum_l attn[l] * hist[b][l][d] ----
    if (tid < D_) {
        float acc = 0.f;
        const float* hb = hist + (size_t)b * L_ * D_ + tid;
        #pragma unroll 8
        for (int l = 0; l < L_; ++l)
            acc = fmaf(h0s[l], hb[(size_t)l * D_], acc);
        ui_out[tid] = acc;
    }
}

extern "C" void kernel_launch(void* const* d_in, const int* in_sizes, int n_in,
                              void* d_out, int out_size, void* d_ws, size_t ws_size,
                              hipStream_t stream) {
    const float* hist = (const float*)d_in[0];
    const float* tgt  = (const float*)d_in[1];
    const int*   mask = (const int*)d_in[2];
    const float* W0   = (const float*)d_in[3];
    const float* b0   = (const float*)d_in[4];
    const float* W1   = (const float*)d_in[5];
    const float* b1   = (const float*)d_in[6];
    const float* W2   = (const float*)d_in[7];
    const float* b2   = (const float*)d_in[8];
    din_kernel<<<B_, 256, 0, stream>>>(hist, tgt, mask, W0, b0, W1, b1, W2, b2,
                                       (float*)d_out);
}

// Round 2
// 400.486 us; speedup vs baseline: 1.6477x; 1.6477x over previous
//
#include <hip/hip_runtime.h>
#include <hip/hip_bf16.h>

#define B_  2048
#define L_  200
#define D_  128
#define H0_ 80
#define H1_ 40

typedef __attribute__((ext_vector_type(8))) short short8;
typedef __attribute__((ext_vector_type(4))) float floatx4;

__device__ __forceinline__ short f2bf(float f) {
    unsigned u = __float_as_uint(f);
    u += 0x7fffu + ((u >> 16) & 1u);   // round-to-nearest-even
    return (short)(u >> 16);
}

// One block per batch b; 4 waves. Layer0 factorization:
// feat@W0 = hist@(W0a+W0c+diag(tgt)W0d) + [tgt@(W0b-W0c)+b0]
// Layers 0+1 on MFMA (bf16), layer 2 + softmax + weighted sum fp32 VALU.
__global__ __launch_bounds__(256, 3) void din_kernel(
    const float* __restrict__ hist,   // (B,L,D)
    const float* __restrict__ tgt,    // (B,D)
    const int*   __restrict__ mask,   // (B,L)
    const float* __restrict__ W0,     // (512,80)
    const float* __restrict__ b0,     // (80)
    const float* __restrict__ W1,     // (80,40)
    const float* __restrict__ b1,     // (40)
    const float* __restrict__ W2,     // (40,1)
    const float* __restrict__ b2,     // (1)
    float* __restrict__ out)          // [B*128 ui | B*200 attn]
{
    // LDS ~49.6 KB -> 3 blocks/CU
    __shared__ __align__(16) short w0t[H0_][136];    // W0eff^T [n][k], pad->2-way banks
    __shared__ __align__(16) short w1t[48][104];     // W1^T [n][k], zero-padded
    __shared__ __align__(16) short h0t[4][16][104];  // per-wave h0 tile [m][k], k>=80 zero
    __shared__ float tgs[D_];
    __shared__ float beffp[2][H0_];
    __shared__ float beffs[H0_];
    __shared__ float b1w2[2][48];                    // b1 / w2, zero-padded
    __shared__ float scores[208];
    __shared__ float attns[L_];
    __shared__ float partial[2][D_];
    __shared__ float red[8];

    const int tid = threadIdx.x;
    const int b   = blockIdx.x;
    float* ui_out   = out + (size_t)b * D_;
    float* attn_out = out + (size_t)B_ * D_ + (size_t)b * L_;

    // ---- stage constants ----
    if (tid < D_) tgs[tid] = tgt[(size_t)b * D_ + tid];
    if (tid < 48) {
        b1w2[0][tid] = (tid < H1_) ? b1[tid] : 0.f;
        b1w2[1][tid] = (tid < H1_) ? W2[tid] : 0.f;
    }
    for (int i = tid; i < 48 * 104; i += 256) {
        int n = i / 104, k = i - n * 104;
        w1t[n][k] = (n < H1_ && k < H0_) ? f2bf(W1[k * H1_ + n]) : (short)0;
    }
    for (int i = tid; i < 4 * 16 * 104 / 2; i += 256) ((int*)h0t)[i] = 0;
    __syncthreads();

    // ---- build W0eff^T (bf16) + beff partials ----
    for (int i = tid; i < D_ * H0_; i += 256) {       // i = d*80+h
        int d = i / H0_, h = i - d * H0_;
        float v = W0[i] + W0[256 * H0_ + i] + tgs[d] * W0[384 * H0_ + i];
        w0t[h][d] = f2bf(v);
    }
    if (tid < 160) {
        int h = tid % H0_, c = tid / H0_;
        float s = 0.f;
        #pragma unroll 4
        for (int d = c * 64; d < c * 64 + 64; ++d)
            s += tgs[d] * (W0[(128 + d) * H0_ + h] - W0[(256 + d) * H0_ + h]);
        beffp[c][h] = s;
    }
    __syncthreads();
    if (tid < H0_) beffs[tid] = b0[tid] + beffp[0][tid] + beffp[1][tid];
    __syncthreads();

    // ---- MFMA layers 0+1 + layer-2 reduce, per-wave m-tiles ----
    const int wave = tid >> 6, lane = tid & 63;
    const int col = lane & 15, quad = lane >> 4;
    const float b2v = b2[0];

    for (int mt = wave; mt < 13; mt += 4) {
        const int m0 = mt * 16;
        int mrow = m0 + col; if (mrow > L_ - 1) mrow = L_ - 1;
        const float* ap = hist + ((size_t)b * L_ + mrow) * D_ + quad * 8;

        short8 afrag[4];
        #pragma unroll
        for (int ks = 0; ks < 4; ++ks) {
            floatx4 x = *(const floatx4*)(ap + ks * 32);
            floatx4 y = *(const floatx4*)(ap + ks * 32 + 4);
            short8 a;
            a[0] = f2bf(x[0]); a[1] = f2bf(x[1]); a[2] = f2bf(x[2]); a[3] = f2bf(x[3]);
            a[4] = f2bf(y[0]); a[5] = f2bf(y[1]); a[6] = f2bf(y[2]); a[7] = f2bf(y[3]);
            afrag[ks] = a;
        }

        floatx4 c0[5];
        #pragma unroll
        for (int nt = 0; nt < 5; ++nt) c0[nt] = (floatx4)0.f;
        #pragma unroll
        for (int ks = 0; ks < 4; ++ks) {
            #pragma unroll
            for (int nt = 0; nt < 5; ++nt) {
                short8 bf = *(const short8*)&w0t[nt * 16 + col][ks * 32 + quad * 8];
                c0[nt] = __builtin_amdgcn_mfma_f32_16x16x32_bf16(afrag[ks], bf, c0[nt], 0, 0, 0);
            }
        }
        // epilogue layer0: bias+relu -> wave-private h0 tile (A-operand layout)
        #pragma unroll
        for (int nt = 0; nt < 5; ++nt) {
            #pragma unroll
            for (int r = 0; r < 4; ++r) {
                float v = c0[nt][r] + beffs[nt * 16 + col];
                v = v > 0.f ? v : 0.f;
                h0t[wave][quad * 4 + r][nt * 16 + col] = f2bf(v);
            }
        }

        floatx4 c1[3];
        #pragma unroll
        for (int nt = 0; nt < 3; ++nt) c1[nt] = (floatx4)0.f;
        #pragma unroll
        for (int ks = 0; ks < 3; ++ks) {
            short8 a1 = *(const short8*)&h0t[wave][col][ks * 32 + quad * 8];
            #pragma unroll
            for (int nt = 0; nt < 3; ++nt) {
                short8 bf = *(const short8*)&w1t[nt * 16 + col][ks * 32 + quad * 8];
                c1[nt] = __builtin_amdgcn_mfma_f32_16x16x32_bf16(a1, bf, c1[nt], 0, 0, 0);
            }
        }
        // layer2: relu(h1)+bias dot w2, reduce over 16 cols
        float s4[4] = {0.f, 0.f, 0.f, 0.f};
        #pragma unroll
        for (int nt = 0; nt < 3; ++nt) {
            float bb = b1w2[0][nt * 16 + col];
            float ww = b1w2[1][nt * 16 + col];
            #pragma unroll
            for (int r = 0; r < 4; ++r) {
                float v = c1[nt][r] + bb;
                v = v > 0.f ? v : 0.f;
                s4[r] += v * ww;
            }
        }
        #pragma unroll
        for (int r = 0; r < 4; ++r) {
            s4[r] += __shfl_xor(s4[r], 1, 16);
            s4[r] += __shfl_xor(s4[r], 2, 16);
            s4[r] += __shfl_xor(s4[r], 4, 16);
            s4[r] += __shfl_xor(s4[r], 8, 16);
        }
        if (col == 0) {
            #pragma unroll
            for (int r = 0; r < 4; ++r)
                scores[m0 + quad * 4 + r] = s4[r] + b2v;
        }
    }
    __syncthreads();

    // ---- softmax over L with mask ----
    float sc;
    if (tid < L_) {
        sc = scores[tid];
        if (mask[(size_t)b * L_ + tid] == 0) sc -= 1e9f;
    } else {
        sc = -3.0e38f;
    }
    float m = sc;
    #pragma unroll
    for (int off = 32; off >= 1; off >>= 1) m = fmaxf(m, __shfl_xor(m, off, 64));
    int wid = tid >> 6;
    if ((tid & 63) == 0) red[wid] = m;
    __syncthreads();
    m = fmaxf(fmaxf(red[0], red[1]), fmaxf(red[2], red[3]));
    float e = (tid < L_) ? __expf(sc - m) : 0.f;
    float s = e;
    #pragma unroll
    for (int off = 32; off >= 1; off >>= 1) s += __shfl_xor(s, off, 64);
    if ((tid & 63) == 0) red[4 + wid] = s;
    __syncthreads();
    s = red[4] + red[5] + red[6] + red[7];
    float inv = 1.0f / s;
    if (tid < L_) {
        float av = e * inv;
        attns[tid] = av;
        attn_out[tid] = av;
    }
    __syncthreads();

    // ---- user_interest: all 4 waves, split L in halves ----
    {
        const int half = tid >> 7, d = tid & 127;
        const float* hb = hist + ((size_t)b * L_ + half * 100) * D_ + d;
        float acc = 0.f;
        #pragma unroll 10
        for (int l = 0; l < 100; ++l)
            acc = fmaf(attns[half * 100 + l], hb[(size_t)l * D_], acc);
        partial[half][d] = acc;
    }
    __syncthreads();
    if (tid < D_) ui_out[tid] = partial[0][tid] + partial[1][tid];
}

extern "C" void kernel_launch(void* const* d_in, const int* in_sizes, int n_in,
                              void* d_out, int out_size, void* d_ws, size_t ws_size,
                              hipStream_t stream) {
    const float* hist = (const float*)d_in[0];
    const float* tgt  = (const float*)d_in[1];
    const int*   mask = (const int*)d_in[2];
    const float* W0   = (const float*)d_in[3];
    const float* b0   = (const float*)d_in[4];
    const float* W1   = (const float*)d_in[5];
    const float* b1   = (const float*)d_in[6];
    const float* W2   = (const float*)d_in[7];
    const float* b2   = (const float*)d_in[8];
    din_kernel<<<B_, 256, 0, stream>>>(hist, tgt, mask, W0, b0, W1, b1, W2, b2,
                                       (float*)d_out);
}